// Round 2
// 1794.469 us; speedup vs baseline: 1.3001x; 1.3001x over previous
//
#include <hip/hip_runtime.h>
#include <hip/hip_fp16.h>

#define EPSF 1e-12f

constexpr int NB = 16;          // batches
constexpr int N  = 2048;        // matrix dim
constexpr int NR = NB * N;      // 32768
constexpr long long NELEM = (long long)NB * N * N;  // 67108864
constexpr int ITERS = 20;
constexpr int CHUNK = 32;       // fallback col-pass rows per block

// ---------------- fp16-E fused-iteration path ----------------
// Per iteration only TWO dispatches:
//   row_pass2: recompute c_cur from (c_prev,t_prev) into LDS (designated
//              block persists c_cur + zeroes t_cur), then row sums -> r
//   col_pass2: col sums weighted by r -> t_cur (LDS pair-combine + atomics)
// Double-buffered c/t make the designated-block writes race-free:
// within a launch every block reads ONLY the prev buffers.

__device__ __forceinline__ float dot8(uint4 hv, float4 cA, float4 cB) {
    const __half2* h2 = reinterpret_cast<const __half2*>(&hv);
    float2 f0 = __half22float2(h2[0]);
    float2 f1 = __half22float2(h2[1]);
    float2 f2 = __half22float2(h2[2]);
    float2 f3 = __half22float2(h2[3]);
    return f0.x*cA.x + f0.y*cA.y + f1.x*cA.z + f1.y*cA.w
         + f2.x*cB.x + f2.y*cB.y + f3.x*cB.z + f3.y*cB.w;
}

// E = exp(A) (fp16), plus r=1 / t0=0 / t1=0 init for the first 32768 threads
__global__ void exp_init(const float* __restrict__ A, __half* __restrict__ E,
                         float* __restrict__ r, float* __restrict__ t0,
                         float* __restrict__ t1) {
    long long v = (long long)blockIdx.x * blockDim.x + threadIdx.x;
    long long g = v * 8;
    float4 a0 = *reinterpret_cast<const float4*>(A + g);
    float4 a1 = *reinterpret_cast<const float4*>(A + g + 4);
    union { __half2 h2[4]; uint4 u; } cvt;
    cvt.h2[0] = __floats2half2_rn(expf(a0.x), expf(a0.y));
    cvt.h2[1] = __floats2half2_rn(expf(a0.z), expf(a0.w));
    cvt.h2[2] = __floats2half2_rn(expf(a1.x), expf(a1.y));
    cvt.h2[3] = __floats2half2_rn(expf(a1.z), expf(a1.w));
    *reinterpret_cast<uint4*>(E + g) = cvt.u;
    if (v < NR) { r[v] = 1.f; t0[v] = 0.f; t1[v] = 0.f; }
}

// 1024 blocks x 256 threads; block bid handles rows [bid*32, bid*32+32)
__global__ __launch_bounds__(256) void row_pass2(
    const __half* __restrict__ E,
    const float* __restrict__ cprev, const float* __restrict__ tprev,
    float* __restrict__ ccur, float* __restrict__ tcur,
    float* __restrict__ r, int k)
{
    __shared__ float sc[N];                       // 8 KiB: this batch's c_cur
    const int tid  = threadIdx.x;
    const int bid  = blockIdx.x;
    const int lane = tid & 63;
    const int wv   = tid >> 6;
    const int b    = bid >> 6;                    // 64 blocks per batch

    // ---- c-update into LDS (redundant per block); one block/batch persists ----
    {
        const float* cp = cprev + (b << 11);
        const float* tp = tprev + (b << 11);
        float* cc = ccur + (b << 11);
        float* tc = tcur + (b << 11);
        const bool desig = ((bid & 63) == 0);
#pragma unroll
        for (int j = tid; j < N; j += 256) {
            float nc;
            if (k == 0) {
                nc = 1.f;                          // first row-normalize: c = 1
            } else {
                float cv = cp[j];
                nc = cv / (cv * tp[j] + EPSF);
            }
            sc[j] = nc;
            if (desig) { cc[j] = nc; tc[j] = 0.f; }
        }
        __syncthreads();
    }

    // ---- row sums: each wave owns 8 rows, processed 4 at a time ----
    const int rowBase = bid * 32 + wv * 8;
#pragma unroll
    for (int g2 = 0; g2 < 2; ++g2) {
        const int R0 = rowBase + g2 * 4;
        const __half* rp0 = E + (long long)(R0 + 0) * N;
        const __half* rp1 = E + (long long)(R0 + 1) * N;
        const __half* rp2 = E + (long long)(R0 + 2) * N;
        const __half* rp3 = E + (long long)(R0 + 3) * N;
        float a0 = 0.f, a1 = 0.f, a2 = 0.f, a3 = 0.f;
#pragma unroll
        for (int q = 0; q < 4; ++q) {
            const int j = q * 512 + lane * 8;
            uint4 h0 = *reinterpret_cast<const uint4*>(rp0 + j);
            uint4 h1 = *reinterpret_cast<const uint4*>(rp1 + j);
            uint4 h2 = *reinterpret_cast<const uint4*>(rp2 + j);
            uint4 h3 = *reinterpret_cast<const uint4*>(rp3 + j);
            float4 cA = *reinterpret_cast<const float4*>(&sc[j]);
            float4 cB = *reinterpret_cast<const float4*>(&sc[j + 4]);
            a0 += dot8(h0, cA, cB);
            a1 += dot8(h1, cA, cB);
            a2 += dot8(h2, cA, cB);
            a3 += dot8(h3, cA, cB);
        }
#pragma unroll
        for (int off = 32; off > 0; off >>= 1) {
            a0 += __shfl_xor(a0, off, 64);
            a1 += __shfl_xor(a1, off, 64);
            a2 += __shfl_xor(a2, off, 64);
            a3 += __shfl_xor(a3, off, 64);
        }
        if (lane == 0) {
            float r0 = r[R0], r1 = r[R0+1], r2 = r[R0+2], r3 = r[R0+3];
            r[R0]   = r0 / (r0 * a0 + EPSF);
            r[R0+1] = r1 / (r1 * a1 + EPSF);
            r[R0+2] = r2 / (r2 * a2 + EPSF);
            r[R0+3] = r3 / (r3 * a3 + EPSF);
        }
    }
}

// 1024 blocks x 256 threads; tile = 1024 cols x 64 rows; LDS pair-combine
// -> 1M atomics/iter, 32 contenders per address (was 2M / 64-way)
__global__ __launch_bounds__(256) void col_pass2(const __half* __restrict__ E,
                                                 const float* __restrict__ r,
                                                 float* __restrict__ tcur)
{
    __shared__ float sp[1024];                    // 4 KiB combine buffer
    const int b    = blockIdx.x >> 6;
    const int tloc = blockIdx.x & 63;
    const int ch   = tloc & 1;                    // column half (1024 cols)
    const int rc   = tloc >> 1;                   // row chunk 0..31 (64 rows)
    const int half = threadIdx.x >> 7;            // row interleave 0..1
    const int cix  = threadIdx.x & 127;           // col group within half
    const int col0 = ch * 1024 + cix * 8;
    const int row0 = rc * 64;
    const __half* base = E + (long long)b * N * N + (long long)row0 * N + col0;
    const float* rb = r + (b << 11) + row0;
    float acc[8] = {0.f,0.f,0.f,0.f,0.f,0.f,0.f,0.f};
#pragma unroll 8
    for (int i = half; i < 64; i += 2) {
        float rv = rb[i];
        uint4 hv = *reinterpret_cast<const uint4*>(base + (long long)i * N);
        const __half2* h2 = reinterpret_cast<const __half2*>(&hv);
        float2 f0 = __half22float2(h2[0]);
        float2 f1 = __half22float2(h2[1]);
        float2 f2 = __half22float2(h2[2]);
        float2 f3 = __half22float2(h2[3]);
        acc[0] += rv * f0.x; acc[1] += rv * f0.y;
        acc[2] += rv * f1.x; acc[3] += rv * f1.y;
        acc[4] += rv * f2.x; acc[5] += rv * f2.y;
        acc[6] += rv * f3.x; acc[7] += rv * f3.y;
    }
    if (half) {
#pragma unroll
        for (int q = 0; q < 8; ++q) sp[cix * 8 + q] = acc[q];
    }
    __syncthreads();
    if (!half) {
        float* tb = tcur + (b << 11) + col0;
#pragma unroll
        for (int q = 0; q < 8; ++q)
            atomicAdd(tb + q, acc[q] + sp[cix * 8 + q]);
    }
}

// out = r_i * E_ij * c_final_j, with c_final = c/(c*t+eps) computed inline
__global__ void out2(const __half* __restrict__ E, const float* __restrict__ r,
                     const float* __restrict__ c, const float* __restrict__ t,
                     float* __restrict__ out) {
    long long g = ((long long)blockIdx.x * blockDim.x + threadIdx.x) * 8;
    int R = (int)(g >> 11);
    int b = R >> 11;
    int j = (int)(g & 2047);
    float rv = r[R];
    const float* cu = c + (b << 11) + j;
    const float* tu = t + (b << 11) + j;
    float4 cA = *reinterpret_cast<const float4*>(cu);
    float4 cB = *reinterpret_cast<const float4*>(cu + 4);
    float4 tA = *reinterpret_cast<const float4*>(tu);
    float4 tB = *reinterpret_cast<const float4*>(tu + 4);
    cA.x = cA.x / (cA.x * tA.x + EPSF);
    cA.y = cA.y / (cA.y * tA.y + EPSF);
    cA.z = cA.z / (cA.z * tA.z + EPSF);
    cA.w = cA.w / (cA.w * tA.w + EPSF);
    cB.x = cB.x / (cB.x * tB.x + EPSF);
    cB.y = cB.y / (cB.y * tB.y + EPSF);
    cB.z = cB.z / (cB.z * tB.z + EPSF);
    cB.w = cB.w / (cB.w * tB.w + EPSF);
    uint4 hv = *reinterpret_cast<const uint4*>(E + g);
    const __half2* h2 = reinterpret_cast<const __half2*>(&hv);
    float2 f0 = __half22float2(h2[0]);
    float2 f1 = __half22float2(h2[1]);
    float2 f2 = __half22float2(h2[2]);
    float2 f3 = __half22float2(h2[3]);
    float4 o0, o1;
    o0.x = rv * f0.x * cA.x; o0.y = rv * f0.y * cA.y;
    o0.z = rv * f1.x * cA.z; o0.w = rv * f1.y * cA.w;
    o1.x = rv * f2.x * cB.x; o1.y = rv * f2.y * cB.y;
    o1.z = rv * f3.x * cB.z; o1.w = rv * f3.y * cB.w;
    *reinterpret_cast<float4*>(out + g)     = o0;
    *reinterpret_cast<float4*>(out + g + 4) = o1;
}

// ================= fallback path: recompute exp(A) every pass ===============

__global__ void init_vecs(float* __restrict__ r, float* __restrict__ c,
                          float* __restrict__ t) {
    int i = blockIdx.x * blockDim.x + threadIdx.x;
    if (i < NR) { r[i] = 1.f; c[i] = 1.f; t[i] = 0.f; }
}

__global__ void c_update(float* __restrict__ c, float* __restrict__ t) {
    int i = blockIdx.x * blockDim.x + threadIdx.x;
    if (i < NR) {
        float cv = c[i], tv = t[i];
        c[i] = cv / (cv * tv + EPSF);
        t[i] = 0.f;
    }
}

__global__ __launch_bounds__(256) void row_pass_f(const float* __restrict__ A,
                                                  const float* __restrict__ c,
                                                  float* __restrict__ r) {
    int lane = threadIdx.x & 63;
    int R = blockIdx.x * 4 + (threadIdx.x >> 6);
    int b = R >> 11;
    const float* row = A + (long long)R * N;
    const float* cb  = c + b * N;
    float acc = 0.f;
#pragma unroll
    for (int k = 0; k < 8; ++k) {
        int j = k * 256 + lane * 4;
        float4 a  = *reinterpret_cast<const float4*>(row + j);
        float4 cv = *reinterpret_cast<const float4*>(cb + j);
        acc += __expf(a.x) * cv.x + __expf(a.y) * cv.y
             + __expf(a.z) * cv.z + __expf(a.w) * cv.w;
    }
#pragma unroll
    for (int off = 32; off > 0; off >>= 1) acc += __shfl_xor(acc, off, 64);
    if (lane == 0) {
        float rv = r[R];
        r[R] = rv / (rv * acc + EPSF);
    }
}

__global__ __launch_bounds__(256) void col_pass_f(const float* __restrict__ A,
                                                  const float* __restrict__ r,
                                                  float* __restrict__ t) {
    int b     = blockIdx.x >> 7;
    int rem   = blockIdx.x & 127;
    int cblk  = rem >> 6;
    int chunk = rem & 63;
    int j0 = cblk * 1024 + threadIdx.x * 4;
    const float* base = A + (long long)b * N * N + (long long)(chunk * CHUNK) * N + j0;
    const float* rb = r + b * N + chunk * CHUNK;
    float acc[4] = {0.f, 0.f, 0.f, 0.f};
#pragma unroll 4
    for (int i = 0; i < CHUNK; ++i) {
        float rv = rb[i];
        float4 a = *reinterpret_cast<const float4*>(base + (long long)i * N);
        acc[0] += rv * __expf(a.x); acc[1] += rv * __expf(a.y);
        acc[2] += rv * __expf(a.z); acc[3] += rv * __expf(a.w);
    }
    float* tb = t + b * N + j0;
#pragma unroll
    for (int k = 0; k < 4; ++k) atomicAdd(tb + k, acc[k]);
}

__global__ void out_f(const float* __restrict__ A, const float* __restrict__ r,
                      const float* __restrict__ c, float* __restrict__ out) {
    long long g = ((long long)blockIdx.x * blockDim.x + threadIdx.x) * 4;
    int R = (int)(g >> 11);
    int b = R >> 11;
    int j = (int)(g & 2047);
    float rv = r[R];
    float4 a  = *reinterpret_cast<const float4*>(A + g);
    float4 cv = *reinterpret_cast<const float4*>(c + b * N + j);
    float4 o;
    o.x = rv * __expf(a.x) * cv.x;
    o.y = rv * __expf(a.y) * cv.y;
    o.z = rv * __expf(a.z) * cv.z;
    o.w = rv * __expf(a.w) * cv.w;
    *reinterpret_cast<float4*>(out + g) = o;
}

extern "C" void kernel_launch(void* const* d_in, const int* in_sizes, int n_in,
                              void* d_out, int out_size, void* d_ws, size_t ws_size,
                              hipStream_t stream) {
    const float* A = (const float*)d_in[0];
    float* out = (float*)d_out;
    char* ws = (char*)d_ws;
    const size_t E_bytes   = (size_t)NELEM * sizeof(__half);   // 128 MiB
    const size_t vec_bytes = (size_t)NR * sizeof(float);       // 128 KiB

    if (ws_size >= E_bytes + 5 * vec_bytes) {
        __half* E = (__half*)ws;
        float* r  = (float*)(ws + E_bytes);
        float* c0 = r + NR;
        float* c1 = c0 + NR;
        float* t0 = c1 + NR;
        float* t1 = t0 + NR;
        exp_init<<<(int)(NELEM / 8 / 256), 256, 0, stream>>>(A, E, r, t0, t1);
        for (int it = 0; it < ITERS; ++it) {
            const float* cprev = (it & 1) ? c0 : c1;
            float*       ccur  = (it & 1) ? c1 : c0;
            const float* tprev = (it & 1) ? t0 : t1;
            float*       tcur  = (it & 1) ? t1 : t0;
            row_pass2<<<1024, 256, 0, stream>>>(E, cprev, tprev, ccur, tcur, r, it);
            col_pass2<<<1024, 256, 0, stream>>>(E, r, tcur);
        }
        // last iteration (it=19, odd): ccur=c1, tcur=t1
        out2<<<(int)(NELEM / 8 / 256), 256, 0, stream>>>(E, r, c1, t1, out);
        return;
    }

    // minimal-workspace fp32 fallback
    float* r = (float*)ws;
    float* c = r + NR;
    float* t = c + NR;
    init_vecs<<<NR / 256, 256, 0, stream>>>(r, c, t);
    for (int it = 0; it < ITERS; ++it) {
        row_pass_f<<<NR / 4, 256, 0, stream>>>(A, c, r);
        col_pass_f<<<NB * 128, 256, 0, stream>>>(A, r, t);
        c_update<<<NR / 256, 256, 0, stream>>>(c, t);
    }
    out_f<<<(int)(NELEM / 4 / 256), 256, 0, stream>>>(A, r, c, out);
}